// Round 5
// baseline (2055.166 us; speedup 1.0000x reference)
//
#include <hip/hip_runtime.h>
#include <hip/hip_fp16.h>

typedef unsigned long long ull;
typedef unsigned int uint;

#define BLOCK 256
#define CHUNK 8192          // edges per P1/P3 block
#define BN 128              // nodes per destination bucket
#define POOLW 32            // pooling graph window per bucket

// ---- fp16 nontemporal helpers ----
__device__ inline float ld_nt_half_f(const __half* p) {
    unsigned short raw = __builtin_nontemporal_load((const unsigned short*)p);
    __half_raw hr; hr.x = raw;
    return __half2float(__half(hr));
}
__device__ inline void st_nt_half(float v, __half* p) {
    __half h = __float2half(v);
    __half_raw hr = *(__half_raw*)&h;
    __builtin_nontemporal_store(hr.x, (unsigned short*)p);
}

// ---- P0: zero sums/cnt ----
__global__ void init_kernel(float* __restrict__ sums, float* __restrict__ cnt, int G) {
    int i = blockIdx.x * BLOCK + threadIdx.x;
    if (i < G * 32) sums[i] = 0.f;
    if (i < G) cnt[i] = 0.f;
}

// ---- P1: per-chunk bucket histogram (LDS atomics only) ----
__global__ void p1_kernel(const int* __restrict__ col, int* __restrict__ cntmat,
                          int nE, int NBUK) {
    __shared__ int hist[1024];
    for (int i = threadIdx.x; i < NBUK; i += BLOCK) hist[i] = 0;
    __syncthreads();
    int base = blockIdx.x * CHUNK;
    for (int i = threadIdx.x; i < CHUNK; i += BLOCK) {
        int e = base + i;
        if (e < nE) {
            int c = __builtin_nontemporal_load(&col[e]);
            atomicAdd(&hist[c >> 7], 1);
        }
    }
    __syncthreads();
    int* rowp = cntmat + (size_t)blockIdx.x * NBUK;
    for (int i = threadIdx.x; i < NBUK; i += BLOCK) rowp[i] = hist[i];
}

// ---- P2a: per-bucket serial scan over chunks (in-place), totals out ----
__global__ void p2a_kernel(int* __restrict__ cntmat, int* __restrict__ tot, int C, int NBUK) {
    int b = blockIdx.x * BLOCK + threadIdx.x;
    if (b >= NBUK) return;
    int run = 0;
    for (int c = 0; c < C; ++c) {
        size_t idx = (size_t)c * NBUK + b;
        int v = cntmat[idx];
        cntmat[idx] = run;     // within-bucket exclusive prefix
        run += v;
    }
    tot[b] = run;
}

// ---- P2b: exclusive scan of bucket totals -> bucket bases bb[] ----
__global__ void p2b_kernel(const int* __restrict__ tot, int* __restrict__ bb, int NBUK, int nE) {
    __shared__ int s[1024];
    int t = threadIdx.x;
    int v = (t < NBUK) ? tot[t] : 0;
    s[t] = v;
    __syncthreads();
    for (int off = 1; off < 1024; off <<= 1) {
        int u = (t >= off) ? s[t - off] : 0;
        __syncthreads();
        s[t] += u;
        __syncthreads();
    }
    if (t < NBUK) bb[t] = s[t] - v;
    if (t == 0) bb[NBUK] = nE;
}

// ---- P3: scatter edges into bucket-sorted order (LDS rank atomics) ----
// entry = [dest_local:7][src:17] << 32 | fp32(w)
__global__ void p3_kernel(const int* __restrict__ row, const int* __restrict__ col,
                          const float* __restrict__ w, const int* __restrict__ cntmat,
                          const int* __restrict__ bb, ull* __restrict__ sorted,
                          int nE, int NBUK) {
    __shared__ int hist[1024];
    __shared__ int off[1024];
    for (int i = threadIdx.x; i < NBUK; i += BLOCK) {
        hist[i] = 0;
        off[i] = cntmat[(size_t)blockIdx.x * NBUK + i] + bb[i];
    }
    __syncthreads();
    int base = blockIdx.x * CHUNK;
    for (int i = threadIdx.x; i < CHUNK; i += BLOCK) {
        int e = base + i;
        if (e < nE) {
            int c = __builtin_nontemporal_load(&col[e]);
            int r = __builtin_nontemporal_load(&row[e]);
            float ww = __builtin_nontemporal_load(&w[e]);
            int b = c >> 7, dl = c & 127;
            int rk = atomicAdd(&hist[b], 1);
            ull ent = ((ull)(((uint)dl << 17) | (uint)r) << 32) | (ull)__float_as_uint(ww);
            __builtin_nontemporal_store(ent, &sorted[off[b] + rk]);
        }
    }
}

// ---- P4: weight-degree per node via bucket gather -> dinv ----
__global__ void p4_kernel(const ull* __restrict__ sorted, const int* __restrict__ bb,
                          float* __restrict__ dinv, int nN) {
    __shared__ float dacc[BN];
    if (threadIdx.x < BN) dacc[threadIdx.x] = 0.f;
    __syncthreads();
    int e0 = bb[blockIdx.x], e1 = bb[blockIdx.x + 1];
    for (int i = e0 + threadIdx.x; i < e1; i += BLOCK) {
        ull ent = __builtin_nontemporal_load(&sorted[i]);
        int dl = (int)(ent >> 49) & 127;
        atomicAdd(&dacc[dl], __uint_as_float((uint)ent));
    }
    __syncthreads();
    if (threadIdx.x < BN) {
        int n = blockIdx.x * BN + threadIdx.x;
        if (n < nN) dinv[n] = rsqrtf(1.0f + dacc[threadIdx.x]);
    }
}

// ---- K1: u1 = dinv * (x @ W1), written as two fp16 half-tables ----
__global__ void k1_kernel(const float* __restrict__ x, const float* __restrict__ W1,
                          const float* __restrict__ dinv, __half* __restrict__ t0,
                          __half* __restrict__ t1, int nN) {
    __shared__ float W1s[4 * 32];
    __shared__ float xS[8 * 4];
    if (threadIdx.x < 128) W1s[threadIdx.x] = W1[threadIdx.x];
    int n0 = blockIdx.x * 8;
    if (threadIdx.x < 32) {
        int n = n0 + (threadIdx.x >> 2);
        xS[threadIdx.x] = (n < nN) ? x[(size_t)n * 4 + (threadIdx.x & 3)] : 0.f;
    }
    __syncthreads();
    int nl = threadIdx.x >> 5, f = threadIdx.x & 31;
    int n = n0 + nl;
    if (n >= nN) return;
    float a = 0.f;
#pragma unroll
    for (int k = 0; k < 4; ++k) a = fmaf(xS[nl * 4 + k], W1s[k * 32 + f], a);
    float u = dinv[n] * a;
    __half* dst = (f < 16) ? t0 : t1;
    dst[(size_t)n * 16 + (f & 15)] = __float2half(u);
}

// ---- aggH: per-bucket LDS-scatter aggregation over one 16-feature half ----
// h = dinv[c]*(acc + u_self) + b ; !LAST: relu -> stage ; LAST: pool
template <int HALF, bool LAST>
__global__ void aggH_kernel(const __half* __restrict__ tbl, const ull* __restrict__ sorted,
                            const int* __restrict__ bb, const float* __restrict__ dinv,
                            const float* __restrict__ bias, __half* __restrict__ stage,
                            const int* __restrict__ batch, float* __restrict__ sums,
                            float* __restrict__ cnt, int nN) {
    __shared__ float acc[BN][17];          // padded: bank = (dl*17+f)&31
    __shared__ float gacc[POOLW][16];
    __shared__ float cacc[POOLW];
    __shared__ int g0s;
    for (int i = threadIdx.x; i < BN * 17; i += BLOCK) ((float*)acc)[i] = 0.f;
    if (LAST) {
        for (int i = threadIdx.x; i < POOLW * 16; i += BLOCK) ((float*)gacc)[i] = 0.f;
        if (threadIdx.x < POOLW) cacc[threadIdx.x] = 0.f;
        if (threadIdx.x == 0) g0s = batch[blockIdx.x * BN];
    }
    __syncthreads();

    int bkt = blockIdx.x;
    int e0 = bb[bkt], e1 = bb[bkt + 1];
    int wv = threadIdx.x >> 6, lane = threadIdx.x & 63;
    int e4 = lane >> 4, f = lane & 15;      // 4 edges x 16 features per wave
    int nloc = e1 - e0;
    int per = (nloc + 3) >> 2;
    int wstart = e0 + wv * per;
    int wend = min(wstart + per, e1);

    int idx = wstart + e4;
    for (; idx + 12 < wend; idx += 16) {    // 4 edges in flight per lane-slot
        ull ent[4]; float v[4];
#pragma unroll
        for (int u = 0; u < 4; ++u) ent[u] = __builtin_nontemporal_load(&sorted[idx + 4 * u]);
#pragma unroll
        for (int u = 0; u < 4; ++u) {
            uint hi = (uint)(ent[u] >> 32);
            v[u] = __half2float(tbl[(size_t)(hi & 0x1FFFFu) * 16 + f]);
        }
#pragma unroll
        for (int u = 0; u < 4; ++u) {
            uint hi = (uint)(ent[u] >> 32);
            atomicAdd(&acc[hi >> 17][f], __uint_as_float((uint)ent[u]) * v[u]);
        }
    }
    for (; idx < wend; idx += 4) {
        ull ent = __builtin_nontemporal_load(&sorted[idx]);
        uint hi = (uint)(ent >> 32);
        float v = __half2float(tbl[(size_t)(hi & 0x1FFFFu) * 16 + f]);
        atomicAdd(&acc[hi >> 17][f], __uint_as_float((uint)ent) * v);
    }
    __syncthreads();

    // epilogue: 256 threads = 16 nodes x 16 features per pass
    int fl = threadIdx.x & 15, sub = threadIdx.x >> 4;
    float bf = bias[HALF * 16 + fl];
    for (int p = 0; p < BN / 16; ++p) {
        int nl = p * 16 + sub;
        int n = bkt * BN + nl;
        if (n >= nN) break;
        float uself = __half2float(tbl[(size_t)n * 16 + fl]);
        float h = dinv[n] * (acc[nl][fl] + uself) + bf;
        if (!LAST) {
            h = fmaxf(h, 0.f);
            st_nt_half(h, &stage[(size_t)n * 32 + HALF * 16 + fl]);
        } else {
            int g = batch[n];
            int off = g - g0s;
            if (off < POOLW) {
                atomicAdd(&gacc[off][fl], h);
                if (fl == 0 && HALF == 0) atomicAdd(&cacc[off], 1.f);
            } else {   // rare: sorted-batch gap exceeded window
                atomicAdd(&sums[(size_t)g * 32 + HALF * 16 + fl], h);
                if (fl == 0 && HALF == 0) atomicAdd(&cnt[g], 1.f);
            }
        }
    }
    if (LAST) {
        __syncthreads();
        int nLast = min(bkt * BN + BN, nN) - 1;
        int range = min(batch[nLast] - g0s, POOLW - 1);
        for (int off = sub; off <= range; off += 16) {
            atomicAdd(&sums[(size_t)(g0s + off) * 32 + HALF * 16 + fl], gacc[off][fl]);
            if (fl == 0 && HALF == 0) atomicAdd(&cnt[g0s + off], cacc[off]);
        }
    }
}

// ---- Kgemm: u' = dinv * (h @ W), h from stage, out as two half-tables ----
__global__ void kgemm_kernel(const __half* __restrict__ stage, const float* __restrict__ W,
                             const float* __restrict__ dinv, __half* __restrict__ t0,
                             __half* __restrict__ t1, int nN) {
    __shared__ float Ws[32 * 32];
    __shared__ float hS[8][33];
    for (int i = threadIdx.x; i < 1024; i += BLOCK) Ws[i] = W[i];
    int n0 = blockIdx.x * 8;
    {
        int nl = threadIdx.x >> 5, k = threadIdx.x & 31;
        int n = n0 + nl;
        hS[nl][k] = (n < nN) ? ld_nt_half_f(&stage[(size_t)n * 32 + k]) : 0.f;
    }
    __syncthreads();
    int nl = threadIdx.x >> 5, f = threadIdx.x & 31;
    int n = n0 + nl;
    if (n >= nN) return;
    float a = 0.f;
#pragma unroll
    for (int k = 0; k < 32; ++k) a = fmaf(hS[nl][k], Ws[k * 32 + f], a);
    float u = dinv[n] * a;
    __half* dst = (f < 16) ? t0 : t1;
    dst[(size_t)n * 16 + (f & 15)] = __float2half(u);
}

// ---- classifier ----
__global__ void final_kernel(const float* __restrict__ sums, const float* __restrict__ cnt,
                             const float* __restrict__ lin_w, const float* __restrict__ lin_b,
                             float* __restrict__ out, int G) {
    int g = blockIdx.x * blockDim.x + threadIdx.x;
    if (g >= G) return;
    float c = fmaxf(cnt[g], 1.0f);
    float inv = 1.0f / c;
    float l0 = lin_b[0], l1 = lin_b[1], l2 = lin_b[2];
#pragma unroll
    for (int f = 0; f < 32; ++f) {
        float m = sums[g * 32 + f] * inv;
        l0 = fmaf(m, lin_w[f * 3 + 0], l0);
        l1 = fmaf(m, lin_w[f * 3 + 1], l1);
        l2 = fmaf(m, lin_w[f * 3 + 2], l2);
    }
    float mx = fmaxf(l0, fmaxf(l1, l2));
    float e0 = expf(l0 - mx), e1 = expf(l1 - mx), e2 = expf(l2 - mx);
    float s = 1.0f / (e0 + e1 + e2);
    out[g * 3 + 0] = e0 * s;
    out[g * 3 + 1] = e1 * s;
    out[g * 3 + 2] = e2 * s;
}

// ---------------- launch ----------------

extern "C" void kernel_launch(void* const* d_in, const int* in_sizes, int n_in,
                              void* d_out, int out_size, void* d_ws, size_t ws_size,
                              hipStream_t stream) {
    const float* x     = (const float*)d_in[0];
    const int*   ei    = (const int*)d_in[1];
    const float* ew    = (const float*)d_in[2];
    const int*   batch = (const int*)d_in[3];
    const float* W1    = (const float*)d_in[4];
    const float* b1    = (const float*)d_in[5];
    const float* W2    = (const float*)d_in[6];
    const float* b2    = (const float*)d_in[7];
    const float* W3    = (const float*)d_in[8];
    const float* b3    = (const float*)d_in[9];
    const float* lin_w = (const float*)d_in[10];
    const float* lin_b = (const float*)d_in[11];
    float* out = (float*)d_out;

    const int nN = in_sizes[0] / 4;       // 100000
    const int nE = in_sizes[2];           // 2500000
    const int G  = out_size / 3;          // 1000
    const int* row = ei;
    const int* col = ei + nE;

    const int NBUK = (nN + BN - 1) / BN;          // 782
    const int C    = (nE + CHUNK - 1) / CHUNK;    // 306

    // workspace layout
    ull*    sorted = (ull*)d_ws;                               // [nE]     20 MB
    int*    cntmat = (int*)(sorted + nE);                      // [C*NBUK] ~1 MB
    int*    tot    = cntmat + (size_t)C * NBUK;                // [NBUK]
    int*    bb     = tot + NBUK;                               // [NBUK+1]
    float*  dinv   = (float*)(bb + NBUK + 1);                  // [nN]
    __half* tA0    = (__half*)(dinv + nN);                     // [nN*16] 3.2 MB
    __half* tA1    = tA0 + (size_t)nN * 16;
    __half* tB0    = tA1 + (size_t)nN * 16;
    __half* tB1    = tB0 + (size_t)nN * 16;
    __half* stage  = tB1 + (size_t)nN * 16;                    // [nN*32] 6.4 MB
    float*  sums   = (float*)(stage + (size_t)nN * 32);        // [G*32]
    float*  cnt    = sums + (size_t)G * 32;                    // [G]

    const int gNode8 = (nN + 7) / 8;

    // ---- build (no global atomics anywhere) ----
    init_kernel<<<(G * 32 + BLOCK - 1) / BLOCK, BLOCK, 0, stream>>>(sums, cnt, G);
    p1_kernel<<<C, BLOCK, 0, stream>>>(col, cntmat, nE, NBUK);
    p2a_kernel<<<(NBUK + BLOCK - 1) / BLOCK, BLOCK, 0, stream>>>(cntmat, tot, C, NBUK);
    p2b_kernel<<<1, 1024, 0, stream>>>(tot, bb, NBUK, nE);
    p3_kernel<<<C, BLOCK, 0, stream>>>(row, col, ew, cntmat, bb, sorted, nE, NBUK);
    p4_kernel<<<NBUK, BLOCK, 0, stream>>>(sorted, bb, dinv, nN);

    // ---- layer 1 (linearity: aggregate u1 = dinv*(x@W1)) ----
    k1_kernel<<<gNode8, BLOCK, 0, stream>>>(x, W1, dinv, tA0, tA1, nN);
    aggH_kernel<0, false><<<NBUK, BLOCK, 0, stream>>>(tA0, sorted, bb, dinv, b1, stage,
                                                      batch, sums, cnt, nN);
    aggH_kernel<1, false><<<NBUK, BLOCK, 0, stream>>>(tA1, sorted, bb, dinv, b1, stage,
                                                      batch, sums, cnt, nN);
    kgemm_kernel<<<gNode8, BLOCK, 0, stream>>>(stage, W2, dinv, tB0, tB1, nN);

    // ---- layer 2 ----
    aggH_kernel<0, false><<<NBUK, BLOCK, 0, stream>>>(tB0, sorted, bb, dinv, b2, stage,
                                                      batch, sums, cnt, nN);
    aggH_kernel<1, false><<<NBUK, BLOCK, 0, stream>>>(tB1, sorted, bb, dinv, b2, stage,
                                                      batch, sums, cnt, nN);
    kgemm_kernel<<<gNode8, BLOCK, 0, stream>>>(stage, W3, dinv, tA0, tA1, nN);

    // ---- layer 3 + pooling ----
    aggH_kernel<0, true><<<NBUK, BLOCK, 0, stream>>>(tA0, sorted, bb, dinv, b3, stage,
                                                     batch, sums, cnt, nN);
    aggH_kernel<1, true><<<NBUK, BLOCK, 0, stream>>>(tA1, sorted, bb, dinv, b3, stage,
                                                     batch, sums, cnt, nN);

    final_kernel<<<(G + BLOCK - 1) / BLOCK, BLOCK, 0, stream>>>(sums, cnt, lin_w, lin_b, out, G);
}

// Round 6
// 622.978 us; speedup vs baseline: 3.2989x; 3.2989x over previous
//
#include <hip/hip_runtime.h>
#include <hip/hip_fp16.h>

typedef unsigned long long ull;
typedef unsigned int uint;

#define BLOCK 256
#define PB 128   // nodes per pooling block

// ---------------- setup ----------------

__global__ void init_kernel(float* __restrict__ sums, float* __restrict__ cnt, int G) {
    int i = blockIdx.x * BLOCK + threadIdx.x;
    if (i < G * 32) sums[i] = 0.f;
    if (i < G) cnt[i] = 0.f;
}

// ONE 64-bit atomic per edge: high 12 bits count, low 52 bits fixed-point(2^32) weight sum.
// Returned old value's count = this edge's rank within its destination row.
__global__ void zero_packed_kernel(ull* __restrict__ packed, int nN) {
    int i = blockIdx.x * BLOCK + threadIdx.x;
    if (i < nN) packed[i] = 0ULL;
}

__global__ void passA_kernel(const int* __restrict__ col, const float* __restrict__ w,
                             ull* __restrict__ packed, int* __restrict__ tmp, int nE) {
    int e = blockIdx.x * BLOCK + threadIdx.x;
    if (e < nE) {
        int c = col[e];
        ull inc = (1ULL << 52) | (ull)((double)w[e] * 4294967296.0);
        ull old = atomicAdd(&packed[c], inc);
        tmp[e] = (int)(old >> 52);
    }
}

__global__ void unpack_kernel(const ull* __restrict__ packed, int* __restrict__ ecnt,
                              float* __restrict__ dinv, int nN) {
    int n = blockIdx.x * BLOCK + threadIdx.x;
    if (n < nN) {
        ull p = packed[n];
        ecnt[n] = (int)(p >> 52);
        float deg = 1.0f + (float)((double)(p & ((1ULL << 52) - 1)) * (1.0 / 4294967296.0));
        dinv[n] = rsqrtf(deg);
    }
}

// ---------------- exclusive scan of ecnt -> rowptr ----------------

__global__ void scanA_kernel(const int* __restrict__ ecnt, int* __restrict__ blkSum, int nN) {
    __shared__ int s[BLOCK];
    int i = blockIdx.x * BLOCK + threadIdx.x;
    s[threadIdx.x] = (i < nN) ? ecnt[i] : 0;
    __syncthreads();
    for (int off = BLOCK / 2; off > 0; off >>= 1) {
        if (threadIdx.x < off) s[threadIdx.x] += s[threadIdx.x + off];
        __syncthreads();
    }
    if (threadIdx.x == 0) blkSum[blockIdx.x] = s[0];
}

__global__ void scanB_kernel(const int* __restrict__ blkSum, int* __restrict__ blkOff,
                             int* __restrict__ rowptr, int NB, int nN) {
    __shared__ int s[512];
    int t = threadIdx.x;
    s[t] = (t < NB) ? blkSum[t] : 0;
    __syncthreads();
    for (int off = 1; off < 512; off <<= 1) {
        int v = (t >= off) ? s[t - off] : 0;
        __syncthreads();
        s[t] += v;
        __syncthreads();
    }
    if (t < NB) blkOff[t] = (t == 0) ? 0 : s[t - 1];
    if (t == 0) rowptr[nN] = s[511];
}

__global__ void scanC_kernel(const int* __restrict__ ecnt, const int* __restrict__ blkOff,
                             int* __restrict__ rowptr, int nN) {
    __shared__ int s[BLOCK];
    int i = blockIdx.x * BLOCK + threadIdx.x;
    int t = threadIdx.x;
    int v = (i < nN) ? ecnt[i] : 0;
    s[t] = v;
    __syncthreads();
    for (int off = 1; off < BLOCK; off <<= 1) {
        int u = (t >= off) ? s[t - off] : 0;
        __syncthreads();
        s[t] += u;
        __syncthreads();
    }
    if (i < nN) rowptr[i] = blkOff[blockIdx.x] + s[t] - v;
}

// atomic-free fill: pos = rowptr[dest] + rank; norm computed here (dinv ready).
__global__ void passB_kernel(const int* __restrict__ row, const int* __restrict__ col,
                             const float* __restrict__ w, const int* __restrict__ rowptr,
                             const int* __restrict__ tmp, const float* __restrict__ dinv,
                             float2* __restrict__ csr, int nE) {
    int e = blockIdx.x * BLOCK + threadIdx.x;
    if (e < nE) {
        int r = row[e], c = col[e];
        int pos = rowptr[c] + tmp[e];
        float nrm = dinv[r] * w[e] * dinv[c];
        csr[pos] = make_float2(__int_as_float(r), nrm);
    }
}

// ---------------- k1: t = x @ W1, written as two fp16 half-tables ----------------

__global__ void k1_kernel(const float* __restrict__ x, const float* __restrict__ W1,
                          __half* __restrict__ t0, __half* __restrict__ t1, int nN) {
    __shared__ float W1s[4 * 32];
    __shared__ float xS[8 * 4];
    if (threadIdx.x < 128) W1s[threadIdx.x] = W1[threadIdx.x];
    int n0 = blockIdx.x * 8;
    if (threadIdx.x < 32) {
        int n = n0 + (threadIdx.x >> 2);
        xS[threadIdx.x] = (n < nN) ? x[(size_t)n * 4 + (threadIdx.x & 3)] : 0.f;
    }
    __syncthreads();
    int nl = threadIdx.x >> 5, f = threadIdx.x & 31;
    int n = n0 + nl;
    if (n >= nN) return;
    float a = 0.f;
#pragma unroll
    for (int k = 0; k < 4; ++k) a = fmaf(xS[nl * 4 + k], W1s[k * 32 + f], a);
    __half* dst = (f < 16) ? t0 : t1;
    dst[(size_t)n * 16 + (f & 15)] = __float2half(a);
}

// ---------------- aggHalf: wave-per-node CSR gather over one 16-feature half ----
// lane = e4*16 + f : 4 edge slots x 16 features. 16 edges in flight per wave.
// tbl is nN x 16 fp16 (3.2 MB -> L2-resident). No LDS, shfl reduction.
// h = agg + bias ; !LAST: relu. stage/bias pointers pre-offset by half*16.

template <bool LAST>
__global__ void aggHalf_kernel(const __half* __restrict__ tbl, const int* __restrict__ rowptr,
                               const float2* __restrict__ csr, const float* __restrict__ dinv,
                               const float* __restrict__ bias, __half* __restrict__ stage,
                               int nN) {
    int wv = threadIdx.x >> 6, lane = threadIdx.x & 63;
    int e4 = lane >> 4, f = lane & 15;
    int n = blockIdx.x * (BLOCK / 64) + wv;
    if (n >= nN) return;                         // wave-uniform exit

    float di = dinv[n];
    int s0 = rowptr[n], s1 = rowptr[n + 1];
    float acc = (e4 == 0) ? di * di * __half2float(tbl[(size_t)n * 16 + f]) : 0.f;

    int j = s0;
    for (; j + 16 <= s1; j += 16) {              // 16 edges in flight
        float2 p[4]; float v[4];
#pragma unroll
        for (int u = 0; u < 4; ++u) p[u] = csr[j + 4 * u + e4];
#pragma unroll
        for (int u = 0; u < 4; ++u) v[u] = __half2float(tbl[(size_t)__float_as_int(p[u].x) * 16 + f]);
#pragma unroll
        for (int u = 0; u < 4; ++u) acc = fmaf(p[u].y, v[u], acc);
    }
    for (; j + 4 <= s1; j += 4) {                // 4 edges in flight
        float2 p = csr[j + e4];
        acc = fmaf(p.y, __half2float(tbl[(size_t)__float_as_int(p.x) * 16 + f]), acc);
    }
    if (j + e4 < s1) {                           // tail (<4 edges)
        float2 p = csr[j + e4];
        acc = fmaf(p.y, __half2float(tbl[(size_t)__float_as_int(p.x) * 16 + f]), acc);
    }

    acc += __shfl_xor(acc, 16);                  // reduce across 4 edge slots
    acc += __shfl_xor(acc, 32);
    float h = acc + bias[f];
    if (!LAST) h = fmaxf(h, 0.f);
    if (lane < 16) stage[(size_t)n * 32 + f] = __float2half(h);
}

// ---------------- kgemm: t' = stage(h, fp16) @ W, out as two half-tables ------

__global__ void kgemm_kernel(const __half* __restrict__ stage, const float* __restrict__ W,
                             __half* __restrict__ t0, __half* __restrict__ t1, int nN) {
    __shared__ float Ws[32 * 32];
    __shared__ float hS[8][33];
    for (int i = threadIdx.x; i < 1024; i += BLOCK) Ws[i] = W[i];
    int n0 = blockIdx.x * 8;
    {
        int nl = threadIdx.x >> 5, k = threadIdx.x & 31;
        int n = n0 + nl;
        hS[nl][k] = (n < nN) ? __half2float(stage[(size_t)n * 32 + k]) : 0.f;
    }
    __syncthreads();
    int nl = threadIdx.x >> 5, f = threadIdx.x & 31;
    int n = n0 + nl;
    if (n >= nN) return;
    float a = 0.f;
#pragma unroll
    for (int k = 0; k < 32; ++k) a = fmaf(hS[nl][k], Ws[k * 32 + f], a);
    __half* dst = (f < 16) ? t0 : t1;
    dst[(size_t)n * 16 + (f & 15)] = __float2half(a);
}

// ---------------- pooling: LDS-privatized (batch sorted), fp16 input ----------

__global__ void pool_kernel(const __half* __restrict__ stage, const int* __restrict__ batch,
                            float* __restrict__ sums, float* __restrict__ cnt, int nN) {
    __shared__ float accS[PB][32];
    __shared__ float cntS[PB];
    __shared__ int g0s;
    int n0 = blockIdx.x * PB;
    for (int i = threadIdx.x; i < PB * 32; i += BLOCK) ((float*)accS)[i] = 0.0f;
    for (int i = threadIdx.x; i < PB; i += BLOCK) cntS[i] = 0.0f;
    if (threadIdx.x == 0) g0s = batch[n0];
    __syncthreads();
    int g0 = g0s;
    int f = threadIdx.x & 31, sub = threadIdx.x >> 5;
    for (int k = 0; k < PB / 8; ++k) {
        int n = n0 + sub + k * 8;
        if (n < nN) {
            int g = batch[n];
            int off = g - g0;
            float v = __half2float(stage[(size_t)n * 32 + f]);
            if (off < PB) {
                atomicAdd(&accS[off][f], v);
                if (f == 0) atomicAdd(&cntS[off], 1.0f);
            } else {   // rare: sorted-batch gap exceeded window
                atomicAdd(&sums[(size_t)g * 32 + f], v);
                if (f == 0) atomicAdd(&cnt[g], 1.0f);
            }
        }
    }
    __syncthreads();
    int nLast = min(n0 + PB, nN) - 1;
    int range = min(batch[nLast] - g0, PB - 1);
    for (int s = sub; s <= range; s += 8) {
        atomicAdd(&sums[(size_t)(g0 + s) * 32 + f], accS[s][f]);
        if (f == 0) atomicAdd(&cnt[g0 + s], cntS[s]);
    }
}

// ---------------- classifier ----------------

__global__ void final_kernel(const float* __restrict__ sums, const float* __restrict__ cnt,
                             const float* __restrict__ lin_w, const float* __restrict__ lin_b,
                             float* __restrict__ out, int G) {
    int g = blockIdx.x * blockDim.x + threadIdx.x;
    if (g >= G) return;
    float c = fmaxf(cnt[g], 1.0f);
    float inv = 1.0f / c;
    float l0 = lin_b[0], l1 = lin_b[1], l2 = lin_b[2];
#pragma unroll
    for (int f = 0; f < 32; ++f) {
        float m = sums[g * 32 + f] * inv;
        l0 = fmaf(m, lin_w[f * 3 + 0], l0);
        l1 = fmaf(m, lin_w[f * 3 + 1], l1);
        l2 = fmaf(m, lin_w[f * 3 + 2], l2);
    }
    float mx = fmaxf(l0, fmaxf(l1, l2));
    float e0 = expf(l0 - mx), e1 = expf(l1 - mx), e2 = expf(l2 - mx);
    float s = 1.0f / (e0 + e1 + e2);
    out[g * 3 + 0] = e0 * s;
    out[g * 3 + 1] = e1 * s;
    out[g * 3 + 2] = e2 * s;
}

// ---------------- launch ----------------

extern "C" void kernel_launch(void* const* d_in, const int* in_sizes, int n_in,
                              void* d_out, int out_size, void* d_ws, size_t ws_size,
                              hipStream_t stream) {
    const float* x     = (const float*)d_in[0];
    const int*   ei    = (const int*)d_in[1];
    const float* ew    = (const float*)d_in[2];
    const int*   batch = (const int*)d_in[3];
    const float* W1    = (const float*)d_in[4];
    const float* b1    = (const float*)d_in[5];
    const float* W2    = (const float*)d_in[6];
    const float* b2    = (const float*)d_in[7];
    const float* W3    = (const float*)d_in[8];
    const float* b3    = (const float*)d_in[9];
    const float* lin_w = (const float*)d_in[10];
    const float* lin_b = (const float*)d_in[11];
    float* out = (float*)d_out;

    const int nN = in_sizes[0] / 4;       // 100000
    const int nE = in_sizes[2];           // 2500000
    const int G  = out_size / 3;          // 1000
    const int* row = ei;
    const int* col = ei + nE;
    const int NB = (nN + BLOCK - 1) / BLOCK;

    // workspace layout (8B-aligned first)
    char* wsb = (char*)d_ws;
    ull*    packed = (ull*)wsb;                                  // [nN]   0.8 MB
    float2* csr    = (float2*)(packed + nN);                     // [nE]   20 MB
    __half* tA0    = (__half*)(csr + nE);                        // [nN*16] 3.2 MB
    __half* tA1    = tA0 + (size_t)nN * 16;                      // 3.2 MB
    __half* tB0    = tA1 + (size_t)nN * 16;                      // 3.2 MB
    __half* tB1    = tB0 + (size_t)nN * 16;                      // 3.2 MB
    __half* stage  = tB1 + (size_t)nN * 16;                      // [nN*32] 6.4 MB
    int*    tmp    = (int*)tB0;                                  // [nE] 10MB, aliases tB0..stage (dead before kgemm/agg writes)
    float*  dinv   = (float*)(stage + (size_t)nN * 32);          // [nN]
    int*    ecnt   = (int*)(dinv + nN);                          // [nN]
    int*    rowptr = ecnt + nN;                                  // [nN+1]
    int*    blkSum = rowptr + nN + 1;                            // [512]
    int*    blkOff = blkSum + 512;                               // [512]
    float*  sums   = (float*)(blkOff + 512);                     // [G*32]
    float*  cnt    = sums + (size_t)G * 32;                      // [G]

    const int gN    = (nN + BLOCK - 1) / BLOCK;
    const int gE    = (nE + BLOCK - 1) / BLOCK;
    const int gAgg  = (nN + 3) / 4;       // 4 waves/block, one node per wave
    const int gN8   = (nN + 7) / 8;

    // ---- build CSR (round-3 proven path) ----
    init_kernel<<<(G * 32 + BLOCK - 1) / BLOCK, BLOCK, 0, stream>>>(sums, cnt, G);
    zero_packed_kernel<<<gN, BLOCK, 0, stream>>>(packed, nN);
    passA_kernel<<<gE, BLOCK, 0, stream>>>(col, ew, packed, tmp, nE);
    unpack_kernel<<<gN, BLOCK, 0, stream>>>(packed, ecnt, dinv, nN);
    scanA_kernel<<<NB, BLOCK, 0, stream>>>(ecnt, blkSum, nN);
    scanB_kernel<<<1, 512, 0, stream>>>(blkSum, blkOff, rowptr, NB, nN);
    scanC_kernel<<<NB, BLOCK, 0, stream>>>(ecnt, blkOff, rowptr, nN);
    passB_kernel<<<gE, BLOCK, 0, stream>>>(row, col, ew, rowptr, tmp, dinv, csr, nE);

    // ---- layer 1 ----
    k1_kernel<<<gN8, BLOCK, 0, stream>>>(x, W1, tA0, tA1, nN);
    aggHalf_kernel<false><<<gAgg, BLOCK, 0, stream>>>(tA0, rowptr, csr, dinv, b1, stage, nN);
    aggHalf_kernel<false><<<gAgg, BLOCK, 0, stream>>>(tA1, rowptr, csr, dinv, b1 + 16, stage + 16, nN);
    kgemm_kernel<<<gN8, BLOCK, 0, stream>>>(stage, W2, tB0, tB1, nN);

    // ---- layer 2 ----
    aggHalf_kernel<false><<<gAgg, BLOCK, 0, stream>>>(tB0, rowptr, csr, dinv, b2, stage, nN);
    aggHalf_kernel<false><<<gAgg, BLOCK, 0, stream>>>(tB1, rowptr, csr, dinv, b2 + 16, stage + 16, nN);
    kgemm_kernel<<<gN8, BLOCK, 0, stream>>>(stage, W3, tA0, tA1, nN);

    // ---- layer 3 (no relu) + pooling ----
    aggHalf_kernel<true><<<gAgg, BLOCK, 0, stream>>>(tA0, rowptr, csr, dinv, b3, stage, nN);
    aggHalf_kernel<true><<<gAgg, BLOCK, 0, stream>>>(tA1, rowptr, csr, dinv, b3 + 16, stage + 16, nN);

    pool_kernel<<<(nN + PB - 1) / PB, BLOCK, 0, stream>>>(stage, batch, sums, cnt, nN);
    final_kernel<<<(G + BLOCK - 1) / BLOCK, BLOCK, 0, stream>>>(sums, cnt, lin_w, lin_b, out, G);
}

// Round 7
// 405.140 us; speedup vs baseline: 5.0727x; 1.5377x over previous
//
#include <hip/hip_runtime.h>
#include <hip/hip_fp16.h>

typedef unsigned long long ull;
typedef unsigned int uint;

#define BLOCK 256
#define CHUNK 8192    // edges per p1/p3 block
#define BN 128        // nodes per destination bucket
#define PB 128        // nodes per pooling block

// ---- init: zero sums/cnt ----
__global__ void init_kernel(float* __restrict__ sums, float* __restrict__ cnt, int G) {
    int i = blockIdx.x * BLOCK + threadIdx.x;
    if (i < G * 32) sums[i] = 0.f;
    if (i < G) cnt[i] = 0.f;
}

// ---- p1: per-chunk bucket histogram (LDS atomics only) ----
__global__ void p1_kernel(const int* __restrict__ col, int* __restrict__ cntmat,
                          int nE, int NBUK) {
    __shared__ int hist[1024];
    for (int i = threadIdx.x; i < NBUK; i += BLOCK) hist[i] = 0;
    __syncthreads();
    int base = blockIdx.x * CHUNK;
    int end = min(base + CHUNK, nE);
    for (int e = base + threadIdx.x; e < end; e += BLOCK)
        atomicAdd(&hist[col[e] >> 7], 1);
    __syncthreads();
    for (int i = threadIdx.x; i < NBUK; i += BLOCK)
        cntmat[(size_t)blockIdx.x * NBUK + i] = hist[i];
}

// ---- p2a: per-bucket scan over chunks, one WAVE per bucket (parallel) ----
__global__ void p2a_kernel(int* __restrict__ cntmat, int* __restrict__ tot, int C, int NBUK) {
    int wv = threadIdx.x >> 6, lane = threadIdx.x & 63;
    int b = blockIdx.x * 4 + wv;
    if (b >= NBUK) return;               // wave-uniform
    int running = 0;
    for (int seg = 0; seg < C; seg += 64) {
        int c = seg + lane;
        int v = (c < C) ? cntmat[(size_t)c * NBUK + b] : 0;
        int s = v;
#pragma unroll
        for (int off = 1; off < 64; off <<= 1) {
            int u = __shfl_up(s, off);
            if (lane >= off) s += u;
        }
        if (c < C) cntmat[(size_t)c * NBUK + b] = running + (s - v);  // exclusive
        running += __shfl(s, 63);
    }
    if (lane == 0) tot[b] = running;
}

// ---- p2b: exclusive scan of bucket totals -> bucket bases bb[] ----
__global__ void p2b_kernel(const int* __restrict__ tot, int* __restrict__ bb, int NBUK, int nE) {
    __shared__ int s[1024];
    int t = threadIdx.x;
    int v = (t < NBUK) ? tot[t] : 0;
    s[t] = v;
    __syncthreads();
    for (int off = 1; off < 1024; off <<= 1) {
        int u = (t >= off) ? s[t - off] : 0;
        __syncthreads();
        s[t] += u;
        __syncthreads();
    }
    if (t < NBUK) bb[t] = s[t] - v;
    if (t == 0) bb[NBUK] = nE;
}

// ---- p3: scatter edges into bucket-sorted order ----
// entry = [dl:7][src:17] << 32 | fp32(w). Each bucket slice of this chunk is
// written by exactly one block -> temporally clustered, write-combines well.
__global__ void p3_kernel(const int* __restrict__ row, const int* __restrict__ col,
                          const float* __restrict__ w, const int* __restrict__ cntmat,
                          const int* __restrict__ bb, ull* __restrict__ sorted,
                          int nE, int NBUK) {
    __shared__ int cur[1024];
    for (int i = threadIdx.x; i < NBUK; i += BLOCK)
        cur[i] = cntmat[(size_t)blockIdx.x * NBUK + i] + bb[i];
    __syncthreads();
    int base = blockIdx.x * CHUNK;
    int end = min(base + CHUNK, nE);
    for (int e = base + threadIdx.x; e < end; e += BLOCK) {
        int c = col[e], r = row[e];
        float ww = w[e];
        int b = c >> 7;
        int rk = atomicAdd(&cur[b], 1);
        ull ent = ((ull)(((uint)(c & 127) << 17) | (uint)r) << 32) | (ull)__float_as_uint(ww);
        sorted[rk] = ent;
    }
}

// ---- p4a: per-bucket weight-degree -> dinv, and per-node rowptr ----
__global__ void p4a_kernel(const ull* __restrict__ sorted, const int* __restrict__ bb,
                           float* __restrict__ dinv, int* __restrict__ rowptr, int nN) {
    __shared__ float wsum[BN];
    __shared__ int cntL[BN];
    __shared__ int scanS[BN];
    if (threadIdx.x < BN) { wsum[threadIdx.x] = 0.f; cntL[threadIdx.x] = 0; }
    __syncthreads();
    int b = blockIdx.x;
    int e0 = bb[b], e1 = bb[b + 1];
    for (int i = e0 + threadIdx.x; i < e1; i += BLOCK) {
        ull ent = sorted[i];
        int dl = (int)(ent >> 49) & 127;
        atomicAdd(&cntL[dl], 1);
        atomicAdd(&wsum[dl], __uint_as_float((uint)ent));
    }
    __syncthreads();
    if (threadIdx.x < BN) scanS[threadIdx.x] = cntL[threadIdx.x];
    __syncthreads();
    for (int off = 1; off < BN; off <<= 1) {
        int u = 0;
        if (threadIdx.x < BN && threadIdx.x >= off) u = scanS[threadIdx.x - off];
        __syncthreads();
        if (threadIdx.x < BN) scanS[threadIdx.x] += u;
        __syncthreads();
    }
    if (threadIdx.x < BN) {
        int n = b * BN + threadIdx.x;
        if (n < nN) {
            dinv[n] = rsqrtf(1.0f + wsum[threadIdx.x]);
            rowptr[n] = e0 + scanS[threadIdx.x] - cntL[threadIdx.x];   // exclusive
        }
    }
}

// ---- p4b: bucket-local rank -> final csr (src, norm); no global atomics ----
__global__ void p4b_kernel(const ull* __restrict__ sorted, const int* __restrict__ bb,
                           const int* __restrict__ rowptr, const float* __restrict__ dinv,
                           float2* __restrict__ csr, int nN) {
    __shared__ int cur[BN];
    __shared__ float dinvL[BN];
    int b = blockIdx.x;
    if (threadIdx.x < BN) {
        int n = b * BN + threadIdx.x;
        cur[threadIdx.x] = (n < nN) ? rowptr[n] : 0;
        dinvL[threadIdx.x] = (n < nN) ? dinv[n] : 0.f;
    }
    __syncthreads();
    int e0 = bb[b], e1 = bb[b + 1];
    for (int i = e0 + threadIdx.x; i < e1; i += BLOCK) {
        ull ent = sorted[i];
        int dl = (int)(ent >> 49) & 127;
        int src = (int)(ent >> 32) & 0x1FFFF;
        float ww = __uint_as_float((uint)ent);
        int pos = atomicAdd(&cur[dl], 1);
        float nrm = dinv[src] * ww * dinvL[dl];
        csr[pos] = make_float2(__int_as_float(src), nrm);
    }
}

// ---- layer 1 (fused, validated r3): agg(x) @ W1 + b1, relu, @W2 -> t_next fp16 ----
__global__ void layer1_pass(const float* __restrict__ x, const int* __restrict__ rowptr,
                            const float2* __restrict__ csr, const float* __restrict__ dinv,
                            const float* __restrict__ W1, const float* __restrict__ b1,
                            const float* __restrict__ W2, __half* __restrict__ t_next, int nN) {
    __shared__ float W1s[4 * 32];
    __shared__ float W2s[32 * 32];
    __shared__ float b1s[32];
    __shared__ float hS[BLOCK / 64][32];
    if (threadIdx.x < 128) W1s[threadIdx.x] = W1[threadIdx.x];
    for (int i = threadIdx.x; i < 32 * 32; i += BLOCK) W2s[i] = W2[i];
    if (threadIdx.x < 32) b1s[threadIdx.x] = b1[threadIdx.x];
    __syncthreads();

    int wv = threadIdx.x >> 6, lane = threadIdx.x & 63;
    int n = blockIdx.x * (BLOCK / 64) + wv;
    if (n >= nN) return;

    int el = lane >> 2, comp = lane & 3;        // 16 edge slots x 4 components
    float di = dinv[n];
    int s0 = rowptr[n], s1 = rowptr[n + 1];
    float acc = (el == 0) ? di * di * x[(size_t)n * 4 + comp] : 0.0f;
    int j = s0;
    for (; j + 32 <= s1; j += 32) {
        float2 pa = csr[j + el], pb = csr[j + 16 + el];
        acc = fmaf(pa.y, x[(size_t)__float_as_int(pa.x) * 4 + comp], acc);
        acc = fmaf(pb.y, x[(size_t)__float_as_int(pb.x) * 4 + comp], acc);
    }
    for (; j + 16 <= s1; j += 16) {
        float2 p = csr[j + el];
        acc = fmaf(p.y, x[(size_t)__float_as_int(p.x) * 4 + comp], acc);
    }
    if (j + el < s1) {
        float2 p = csr[j + el];
        acc = fmaf(p.y, x[(size_t)__float_as_int(p.x) * 4 + comp], acc);
    }
#pragma unroll
    for (int off = 4; off < 64; off <<= 1) acc += __shfl_xor(acc, off);
    float a0 = __shfl(acc, 0), a1 = __shfl(acc, 1), a2c = __shfl(acc, 2), a3 = __shfl(acc, 3);

    int f = lane & 31, e2 = lane >> 5;
    float h = b1s[f];
    h = fmaf(a0, W1s[0 * 32 + f], h);
    h = fmaf(a1, W1s[1 * 32 + f], h);
    h = fmaf(a2c, W1s[2 * 32 + f], h);
    h = fmaf(a3, W1s[3 * 32 + f], h);
    h = fmaxf(h, 0.0f);
    if (lane < 32) hS[wv][f] = h;               // wave-private; DS ops in-order
    float o = 0.0f;
#pragma unroll
    for (int k = 0; k < 16; ++k) {
        int kk = e2 * 16 + k;
        o = fmaf(hS[wv][kk], W2s[kk * 32 + f], o);
    }
    o += __shfl_xor(o, 32);
    if (lane < 32) t_next[(size_t)n * 32 + f] = __float2half(o);
}

// ---- fused layer pass (validated r3): agg over fp16 table + bias (+relu+GEMM) ----
template <bool LAST>
__global__ void layer_pass(const __half* __restrict__ t, const int* __restrict__ rowptr,
                           const float2* __restrict__ csr, const float* __restrict__ dinv,
                           const float* __restrict__ b, const float* __restrict__ W,
                           __half* __restrict__ t_next, __half* __restrict__ stage, int nN) {
    __shared__ float Ws[32 * 32];
    __shared__ float hS[BLOCK / 64][32];
    if (!LAST) {
        for (int i = threadIdx.x; i < 32 * 32; i += BLOCK) Ws[i] = W[i];
        __syncthreads();
    }
    int wv = threadIdx.x >> 6, lane = threadIdx.x & 63;
    int e2 = lane >> 5, f = lane & 31;
    int n = blockIdx.x * (BLOCK / 64) + wv;
    if (n >= nN) return;

    float di = dinv[n];
    int s0 = rowptr[n], s1 = rowptr[n + 1];
    float acc = (e2 == 0) ? di * di * __half2float(t[(size_t)n * 32 + f]) : 0.0f;

    int j4 = s0;
    for (; j4 + 16 <= s1; j4 += 16) {           // 16 edges in flight per wave
        float2 p[8]; float v[8];
#pragma unroll
        for (int u = 0; u < 8; ++u) p[u] = csr[j4 + 2 * u + e2];
#pragma unroll
        for (int u = 0; u < 8; ++u) v[u] = __half2float(t[(size_t)__float_as_int(p[u].x) * 32 + f]);
#pragma unroll
        for (int u = 0; u < 8; ++u) acc = fmaf(p[u].y, v[u], acc);
    }
    for (; j4 + 4 <= s1; j4 += 4) {
        float2 p[2]; float v[2];
#pragma unroll
        for (int u = 0; u < 2; ++u) p[u] = csr[j4 + 2 * u + e2];
#pragma unroll
        for (int u = 0; u < 2; ++u) v[u] = __half2float(t[(size_t)__float_as_int(p[u].x) * 32 + f]);
#pragma unroll
        for (int u = 0; u < 2; ++u) acc = fmaf(p[u].y, v[u], acc);
    }
    for (int j = j4 + e2; j < s1; j += 2) {
        float2 p = csr[j];
        acc = fmaf(p.y, __half2float(t[(size_t)__float_as_int(p.x) * 32 + f]), acc);
    }

    acc += __shfl_xor(acc, 32);
    float h = acc + b[f];

    if (LAST) {
        if (lane < 32) stage[(size_t)n * 32 + f] = __float2half(h);
    } else {
        h = fmaxf(h, 0.0f);
        if (lane < 32) hS[wv][f] = h;
        float o = 0.0f;
#pragma unroll
        for (int k = 0; k < 16; ++k) {
            int kk = e2 * 16 + k;
            o = fmaf(hS[wv][kk], Ws[kk * 32 + f], o);
        }
        o += __shfl_xor(o, 32);
        if (lane < 32) t_next[(size_t)n * 32 + f] = __float2half(o);
    }
}

// ---- pooling: LDS-privatized windows (batch sorted), fp16 input ----
__global__ void pool_kernel(const __half* __restrict__ stage, const int* __restrict__ batch,
                            float* __restrict__ sums, float* __restrict__ cnt, int nN) {
    __shared__ float accS[PB][32];
    __shared__ float cntS[PB];
    __shared__ int g0s;
    int n0 = blockIdx.x * PB;
    for (int i = threadIdx.x; i < PB * 32; i += BLOCK) ((float*)accS)[i] = 0.0f;
    for (int i = threadIdx.x; i < PB; i += BLOCK) cntS[i] = 0.0f;
    if (threadIdx.x == 0) g0s = batch[n0];
    __syncthreads();
    int g0 = g0s;
    int f = threadIdx.x & 31, sub = threadIdx.x >> 5;
    for (int k = 0; k < PB / 8; ++k) {
        int n = n0 + sub + k * 8;
        if (n < nN) {
            int g = batch[n];
            int off = g - g0;
            float v = __half2float(stage[(size_t)n * 32 + f]);
            if (off < PB) {
                atomicAdd(&accS[off][f], v);
                if (f == 0) atomicAdd(&cntS[off], 1.0f);
            } else {
                atomicAdd(&sums[(size_t)g * 32 + f], v);
                if (f == 0) atomicAdd(&cnt[g], 1.0f);
            }
        }
    }
    __syncthreads();
    int nLast = min(n0 + PB, nN) - 1;
    int range = min(batch[nLast] - g0, PB - 1);
    for (int s = sub; s <= range; s += 8) {
        atomicAdd(&sums[(size_t)(g0 + s) * 32 + f], accS[s][f]);
        if (f == 0) atomicAdd(&cnt[g0 + s], cntS[s]);
    }
}

// ---- classifier ----
__global__ void final_kernel(const float* __restrict__ sums, const float* __restrict__ cnt,
                             const float* __restrict__ lin_w, const float* __restrict__ lin_b,
                             float* __restrict__ out, int G) {
    int g = blockIdx.x * blockDim.x + threadIdx.x;
    if (g >= G) return;
    float c = fmaxf(cnt[g], 1.0f);
    float inv = 1.0f / c;
    float l0 = lin_b[0], l1 = lin_b[1], l2 = lin_b[2];
#pragma unroll
    for (int f = 0; f < 32; ++f) {
        float m = sums[g * 32 + f] * inv;
        l0 = fmaf(m, lin_w[f * 3 + 0], l0);
        l1 = fmaf(m, lin_w[f * 3 + 1], l1);
        l2 = fmaf(m, lin_w[f * 3 + 2], l2);
    }
    float mx = fmaxf(l0, fmaxf(l1, l2));
    float e0 = expf(l0 - mx), e1 = expf(l1 - mx), e2 = expf(l2 - mx);
    float s = 1.0f / (e0 + e1 + e2);
    out[g * 3 + 0] = e0 * s;
    out[g * 3 + 1] = e1 * s;
    out[g * 3 + 2] = e2 * s;
}

// ---------------- launch ----------------

extern "C" void kernel_launch(void* const* d_in, const int* in_sizes, int n_in,
                              void* d_out, int out_size, void* d_ws, size_t ws_size,
                              hipStream_t stream) {
    const float* x     = (const float*)d_in[0];
    const int*   ei    = (const int*)d_in[1];
    const float* ew    = (const float*)d_in[2];
    const int*   batch = (const int*)d_in[3];
    const float* W1    = (const float*)d_in[4];
    const float* b1    = (const float*)d_in[5];
    const float* W2    = (const float*)d_in[6];
    const float* b2    = (const float*)d_in[7];
    const float* W3    = (const float*)d_in[8];
    const float* b3    = (const float*)d_in[9];
    const float* lin_w = (const float*)d_in[10];
    const float* lin_b = (const float*)d_in[11];
    float* out = (float*)d_out;

    const int nN = in_sizes[0] / 4;       // 100000
    const int nE = in_sizes[2];           // 2500000
    const int G  = out_size / 3;          // 1000
    const int* row = ei;
    const int* col = ei + nE;

    const int NBUK = (nN + BN - 1) / BN;          // 782
    const int C    = (nE + CHUNK - 1) / CHUNK;    // 306

    // workspace layout (8B-aligned first)
    char* wsb = (char*)d_ws;
    ull*    sorted = (ull*)wsb;                                  // [nE]    20 MB
    float2* csr    = (float2*)(sorted + nE);                     // [nE]    20 MB
    __half* t_a    = (__half*)(csr + nE);                        // [nN*32] 6.4 MB
    __half* t_b    = t_a + (size_t)nN * 32;                      // [nN*32] 6.4 MB
    __half* stage  = t_b + (size_t)nN * 32;                      // [nN*32] 6.4 MB
    int*    cntmat = (int*)(stage + (size_t)nN * 32);            // [C*NBUK] ~1 MB
    int*    tot    = cntmat + (size_t)C * NBUK;                  // [NBUK]
    int*    bb     = tot + NBUK;                                 // [NBUK+1]
    float*  dinv   = (float*)(bb + NBUK + 1);                    // [nN]
    int*    rowptr = (int*)(dinv + nN);                          // [nN+1]
    float*  sums   = (float*)(rowptr + nN + 1);                  // [G*32]
    float*  cnt    = sums + (size_t)G * 32;                      // [G]

    const int gW = (nN + (BLOCK / 64) - 1) / (BLOCK / 64);       // one wave per node

    // ---- build: counting sort by destination bucket, zero global atomics ----
    init_kernel<<<(G * 32 + BLOCK - 1) / BLOCK, BLOCK, 0, stream>>>(sums, cnt, G);
    p1_kernel<<<C, BLOCK, 0, stream>>>(col, cntmat, nE, NBUK);
    p2a_kernel<<<(NBUK + 3) / 4, BLOCK, 0, stream>>>(cntmat, tot, C, NBUK);
    p2b_kernel<<<1, 1024, 0, stream>>>(tot, bb, NBUK, nE);
    p3_kernel<<<C, BLOCK, 0, stream>>>(row, col, ew, cntmat, bb, sorted, nE, NBUK);
    p4a_kernel<<<NBUK, BLOCK, 0, stream>>>(sorted, bb, dinv, rowptr, nN);
    p4b_kernel<<<NBUK, BLOCK, 0, stream>>>(sorted, bb, rowptr, dinv, csr, nN);

    // ---- layers (fused r3 structure) ----
    layer1_pass<<<gW, BLOCK, 0, stream>>>(x, rowptr, csr, dinv, W1, b1, W2, t_b, nN);
    layer_pass<false><<<gW, BLOCK, 0, stream>>>(t_b, rowptr, csr, dinv, b2, W3, t_a, nullptr, nN);
    layer_pass<true><<<gW, BLOCK, 0, stream>>>(t_a, rowptr, csr, dinv, b3, nullptr, nullptr, stage, nN);

    // ---- pooling + classifier ----
    pool_kernel<<<(nN + PB - 1) / PB, BLOCK, 0, stream>>>(stage, batch, sums, cnt, nN);
    final_kernel<<<(G + BLOCK - 1) / BLOCK, BLOCK, 0, stream>>>(sums, cnt, lin_w, lin_b, out, G);
}

// Round 8
// 376.993 us; speedup vs baseline: 5.4515x; 1.0747x over previous
//
#include <hip/hip_runtime.h>
#include <hip/hip_fp16.h>

typedef unsigned long long ull;
typedef unsigned int uint;

#define BLOCK 256
#define CHUNK 8192    // edges per p1/p3 block
#define BN 128        // nodes per destination bucket
#define PB 128        // nodes per pooling block
#define WINV (1.0f / 32768.0f)

// ---- init: zero sums/cnt, set rowptr tail ----
__global__ void init_kernel(float* __restrict__ sums, float* __restrict__ cnt,
                            int* __restrict__ rowptr, int G, int nN, int nE) {
    int i = blockIdx.x * BLOCK + threadIdx.x;
    if (i < G * 32) sums[i] = 0.f;
    if (i < G) cnt[i] = 0.f;
    if (i == 0) rowptr[nN] = nE;
}

// ---- p1: per-chunk bucket histogram (LDS atomics only) ----
__global__ void p1_kernel(const int* __restrict__ col, int* __restrict__ cntmat,
                          int nE, int NBUK) {
    __shared__ int hist[1024];
    for (int i = threadIdx.x; i < NBUK; i += BLOCK) hist[i] = 0;
    __syncthreads();
    int base = blockIdx.x * CHUNK;
    int end = min(base + CHUNK, nE);
    for (int e = base + threadIdx.x; e < end; e += BLOCK)
        atomicAdd(&hist[col[e] >> 7], 1);
    __syncthreads();
    for (int i = threadIdx.x; i < NBUK; i += BLOCK)
        cntmat[(size_t)blockIdx.x * NBUK + i] = hist[i];
}

// ---- p2a: per-bucket scan over chunks, one wave per bucket ----
__global__ void p2a_kernel(int* __restrict__ cntmat, int* __restrict__ tot, int C, int NBUK) {
    int wv = threadIdx.x >> 6, lane = threadIdx.x & 63;
    int b = blockIdx.x * 4 + wv;
    if (b >= NBUK) return;
    int running = 0;
    for (int seg = 0; seg < C; seg += 64) {
        int c = seg + lane;
        int v = (c < C) ? cntmat[(size_t)c * NBUK + b] : 0;
        int s = v;
#pragma unroll
        for (int off = 1; off < 64; off <<= 1) {
            int u = __shfl_up(s, off);
            if (lane >= off) s += u;
        }
        if (c < C) cntmat[(size_t)c * NBUK + b] = running + (s - v);
        running += __shfl(s, 63);
    }
    if (lane == 0) tot[b] = running;
}

// ---- p2b: exclusive scan of bucket totals -> bb[] ----
__global__ void p2b_kernel(const int* __restrict__ tot, int* __restrict__ bb, int NBUK, int nE) {
    __shared__ int s[1024];
    int t = threadIdx.x;
    int v = (t < NBUK) ? tot[t] : 0;
    s[t] = v;
    __syncthreads();
    for (int off = 1; off < 1024; off <<= 1) {
        int u = (t >= off) ? s[t - off] : 0;
        __syncthreads();
        s[t] += u;
        __syncthreads();
    }
    if (t < NBUK) bb[t] = s[t] - v;
    if (t == 0) bb[NBUK] = nE;
}

// ---- p3: scatter edges into bucket-sorted order ----
// entry = [dl:7][src:17] << 32 | fp32(w)
__global__ void p3_kernel(const int* __restrict__ row, const int* __restrict__ col,
                          const float* __restrict__ w, const int* __restrict__ cntmat,
                          const int* __restrict__ bb, ull* __restrict__ sorted,
                          int nE, int NBUK) {
    __shared__ int cur[1024];
    for (int i = threadIdx.x; i < NBUK; i += BLOCK)
        cur[i] = cntmat[(size_t)blockIdx.x * NBUK + i] + bb[i];
    __syncthreads();
    int base = blockIdx.x * CHUNK;
    int end = min(base + CHUNK, nE);
    for (int e = base + threadIdx.x; e < end; e += BLOCK) {
        int c = col[e], r = row[e];
        float ww = w[e];
        int b = c >> 7;
        int rk = atomicAdd(&cur[b], 1);
        ull ent = ((ull)(((uint)(c & 127) << 17) | (uint)r) << 32) | (ull)__float_as_uint(ww);
        sorted[rk] = ent;
    }
}

// ---- p4 (merged): degree+dinv+rowptr, then 4-byte csr [src:17][w:15] ----
// Second loop re-reads the bucket slice (L2-hot). No global atomics.
__global__ void p4_kernel(const ull* __restrict__ sorted, const int* __restrict__ bb,
                          float* __restrict__ dinv, int* __restrict__ rowptr,
                          uint* __restrict__ csr4, int nN) {
    __shared__ float wsum[BN];
    __shared__ int cntL[BN];
    __shared__ int scanS[BN];
    __shared__ int cur[BN];
    if (threadIdx.x < BN) { wsum[threadIdx.x] = 0.f; cntL[threadIdx.x] = 0; }
    __syncthreads();
    int b = blockIdx.x;
    int e0 = bb[b], e1 = bb[b + 1];
    for (int i = e0 + threadIdx.x; i < e1; i += BLOCK) {
        ull ent = sorted[i];
        int dl = (int)(ent >> 49) & 127;
        atomicAdd(&cntL[dl], 1);
        atomicAdd(&wsum[dl], __uint_as_float((uint)ent));
    }
    __syncthreads();
    if (threadIdx.x < BN) scanS[threadIdx.x] = cntL[threadIdx.x];
    __syncthreads();
    for (int off = 1; off < BN; off <<= 1) {
        int u = 0;
        if (threadIdx.x < BN && threadIdx.x >= off) u = scanS[threadIdx.x - off];
        __syncthreads();
        if (threadIdx.x < BN) scanS[threadIdx.x] += u;
        __syncthreads();
    }
    if (threadIdx.x < BN) {
        int n = b * BN + threadIdx.x;
        if (n < nN) {
            dinv[n] = rsqrtf(1.0f + wsum[threadIdx.x]);
            int rp = e0 + scanS[threadIdx.x] - cntL[threadIdx.x];
            rowptr[n] = rp;
            cur[threadIdx.x] = rp;
        }
    }
    __syncthreads();
    for (int i = e0 + threadIdx.x; i < e1; i += BLOCK) {
        ull ent = sorted[i];           // L2-hot re-read
        int dl = (int)(ent >> 49) & 127;
        uint src = (uint)(ent >> 32) & 0x1FFFFu;
        float ww = __uint_as_float((uint)ent);
        int wq = min((int)(ww * 32768.0f + 0.5f), 32767);
        int pos = atomicAdd(&cur[dl], 1);
        csr4[pos] = (src << 15) | (uint)wq;
    }
}

// ---- ux: u_x = dinv * x (fp32, 4-wide, 1.6 MB L2-resident) ----
__global__ void ux_kernel(const float* __restrict__ x, const float* __restrict__ dinv,
                          float* __restrict__ u_x, int nN) {
    int i = blockIdx.x * BLOCK + threadIdx.x;
    if (i < nN * 4) u_x[i] = x[i] * dinv[i >> 2];
}

// ---- layer 1: agg(u_x)*di @ W1 + b1, relu, @W2, *di -> u2 fp16 ----
__global__ void layer1_pass(const float* __restrict__ u_x, const int* __restrict__ rowptr,
                            const uint* __restrict__ csr4, const float* __restrict__ dinv,
                            const float* __restrict__ W1, const float* __restrict__ b1,
                            const float* __restrict__ W2, __half* __restrict__ t_next, int nN) {
    __shared__ float W1s[4 * 32];
    __shared__ float W2s[32 * 32];
    __shared__ float b1s[32];
    __shared__ float hS[BLOCK / 64][32];
    if (threadIdx.x < 128) W1s[threadIdx.x] = W1[threadIdx.x];
    for (int i = threadIdx.x; i < 32 * 32; i += BLOCK) W2s[i] = W2[i];
    if (threadIdx.x < 32) b1s[threadIdx.x] = b1[threadIdx.x];
    __syncthreads();

    int wv = threadIdx.x >> 6, lane = threadIdx.x & 63;
    int n = blockIdx.x * (BLOCK / 64) + wv;
    if (n >= nN) return;

    int el = lane >> 2, comp = lane & 3;        // 16 edge slots x 4 components
    float di = dinv[n];
    int s0 = rowptr[n], s1 = rowptr[n + 1];
    float acc = (el == 0) ? u_x[(size_t)n * 4 + comp] : 0.0f;   // self: u_x[n]
    int j = s0;
    for (; j + 32 <= s1; j += 32) {
        uint ea = csr4[j + el], eb = csr4[j + 16 + el];
        acc = fmaf((float)(ea & 32767u) * WINV, u_x[(size_t)(ea >> 15) * 4 + comp], acc);
        acc = fmaf((float)(eb & 32767u) * WINV, u_x[(size_t)(eb >> 15) * 4 + comp], acc);
    }
    for (; j + 16 <= s1; j += 16) {
        uint e = csr4[j + el];
        acc = fmaf((float)(e & 32767u) * WINV, u_x[(size_t)(e >> 15) * 4 + comp], acc);
    }
    if (j + el < s1) {
        uint e = csr4[j + el];
        acc = fmaf((float)(e & 32767u) * WINV, u_x[(size_t)(e >> 15) * 4 + comp], acc);
    }
#pragma unroll
    for (int off = 4; off < 64; off <<= 1) acc += __shfl_xor(acc, off);
    float a0 = di * __shfl(acc, 0), a1 = di * __shfl(acc, 1);
    float a2c = di * __shfl(acc, 2), a3 = di * __shfl(acc, 3);

    int f = lane & 31, e2 = lane >> 5;
    float h = b1s[f];
    h = fmaf(a0, W1s[0 * 32 + f], h);
    h = fmaf(a1, W1s[1 * 32 + f], h);
    h = fmaf(a2c, W1s[2 * 32 + f], h);
    h = fmaf(a3, W1s[3 * 32 + f], h);
    h = fmaxf(h, 0.0f);
    if (lane < 32) hS[wv][f] = h;               // wave-private; DS ops in-order
    float o = 0.0f;
#pragma unroll
    for (int k = 0; k < 16; ++k) {
        int kk = e2 * 16 + k;
        o = fmaf(hS[wv][kk], W2s[kk * 32 + f], o);
    }
    o += __shfl_xor(o, 32);
    if (lane < 32) t_next[(size_t)n * 32 + f] = __float2half(di * o);   // u-table
}

// ---- fused layer pass over fp16 u-table: h = di*(Σ w·u[src] + u[n]) + b ----
template <bool LAST>
__global__ void layer_pass(const __half* __restrict__ t, const int* __restrict__ rowptr,
                           const uint* __restrict__ csr4, const float* __restrict__ dinv,
                           const float* __restrict__ b, const float* __restrict__ W,
                           __half* __restrict__ t_next, __half* __restrict__ stage, int nN) {
    __shared__ float Ws[32 * 32];
    __shared__ float hS[BLOCK / 64][32];
    if (!LAST) {
        for (int i = threadIdx.x; i < 32 * 32; i += BLOCK) Ws[i] = W[i];
        __syncthreads();
    }
    int wv = threadIdx.x >> 6, lane = threadIdx.x & 63;
    int e2 = lane >> 5, f = lane & 31;
    int n = blockIdx.x * (BLOCK / 64) + wv;
    if (n >= nN) return;

    float di = dinv[n];
    int s0 = rowptr[n], s1 = rowptr[n + 1];
    float acc = (e2 == 0) ? __half2float(t[(size_t)n * 32 + f]) : 0.0f;   // self: u[n]

    int j4 = s0;
    for (; j4 + 16 <= s1; j4 += 16) {           // 16 edges in flight per wave
        uint p[8]; float v[8];
#pragma unroll
        for (int u = 0; u < 8; ++u) p[u] = csr4[j4 + 2 * u + e2];
#pragma unroll
        for (int u = 0; u < 8; ++u) v[u] = __half2float(t[(size_t)(p[u] >> 15) * 32 + f]);
#pragma unroll
        for (int u = 0; u < 8; ++u) acc = fmaf((float)(p[u] & 32767u) * WINV, v[u], acc);
    }
    for (; j4 + 4 <= s1; j4 += 4) {
        uint p[2]; float v[2];
#pragma unroll
        for (int u = 0; u < 2; ++u) p[u] = csr4[j4 + 2 * u + e2];
#pragma unroll
        for (int u = 0; u < 2; ++u) v[u] = __half2float(t[(size_t)(p[u] >> 15) * 32 + f]);
#pragma unroll
        for (int u = 0; u < 2; ++u) acc = fmaf((float)(p[u] & 32767u) * WINV, v[u], acc);
    }
    for (int j = j4 + e2; j < s1; j += 2) {
        uint p = csr4[j];
        acc = fmaf((float)(p & 32767u) * WINV, __half2float(t[(size_t)(p >> 15) * 32 + f]), acc);
    }

    acc += __shfl_xor(acc, 32);
    float h = di * acc + b[f];

    if (LAST) {
        if (lane < 32) stage[(size_t)n * 32 + f] = __float2half(h);
    } else {
        h = fmaxf(h, 0.0f);
        if (lane < 32) hS[wv][f] = h;
        float o = 0.0f;
#pragma unroll
        for (int k = 0; k < 16; ++k) {
            int kk = e2 * 16 + k;
            o = fmaf(hS[wv][kk], Ws[kk * 32 + f], o);
        }
        o += __shfl_xor(o, 32);
        if (lane < 32) t_next[(size_t)n * 32 + f] = __float2half(di * o);   // u-table
    }
}

// ---- pooling: LDS-privatized windows (batch sorted), fp16 input ----
__global__ void pool_kernel(const __half* __restrict__ stage, const int* __restrict__ batch,
                            float* __restrict__ sums, float* __restrict__ cnt, int nN) {
    __shared__ float accS[PB][32];
    __shared__ float cntS[PB];
    __shared__ int g0s;
    int n0 = blockIdx.x * PB;
    for (int i = threadIdx.x; i < PB * 32; i += BLOCK) ((float*)accS)[i] = 0.0f;
    for (int i = threadIdx.x; i < PB; i += BLOCK) cntS[i] = 0.0f;
    if (threadIdx.x == 0) g0s = batch[n0];
    __syncthreads();
    int g0 = g0s;
    int f = threadIdx.x & 31, sub = threadIdx.x >> 5;
    for (int k = 0; k < PB / 8; ++k) {
        int n = n0 + sub + k * 8;
        if (n < nN) {
            int g = batch[n];
            int off = g - g0;
            float v = __half2float(stage[(size_t)n * 32 + f]);
            if (off < PB) {
                atomicAdd(&accS[off][f], v);
                if (f == 0) atomicAdd(&cntS[off], 1.0f);
            } else {
                atomicAdd(&sums[(size_t)g * 32 + f], v);
                if (f == 0) atomicAdd(&cnt[g], 1.0f);
            }
        }
    }
    __syncthreads();
    int nLast = min(n0 + PB, nN) - 1;
    int range = min(batch[nLast] - g0, PB - 1);
    for (int s = sub; s <= range; s += 8) {
        atomicAdd(&sums[(size_t)(g0 + s) * 32 + f], accS[s][f]);
        if (f == 0) atomicAdd(&cnt[g0 + s], cntS[s]);
    }
}

// ---- classifier ----
__global__ void final_kernel(const float* __restrict__ sums, const float* __restrict__ cnt,
                             const float* __restrict__ lin_w, const float* __restrict__ lin_b,
                             float* __restrict__ out, int G) {
    int g = blockIdx.x * blockDim.x + threadIdx.x;
    if (g >= G) return;
    float c = fmaxf(cnt[g], 1.0f);
    float inv = 1.0f / c;
    float l0 = lin_b[0], l1 = lin_b[1], l2 = lin_b[2];
#pragma unroll
    for (int f = 0; f < 32; ++f) {
        float m = sums[g * 32 + f] * inv;
        l0 = fmaf(m, lin_w[f * 3 + 0], l0);
        l1 = fmaf(m, lin_w[f * 3 + 1], l1);
        l2 = fmaf(m, lin_w[f * 3 + 2], l2);
    }
    float mx = fmaxf(l0, fmaxf(l1, l2));
    float e0 = expf(l0 - mx), e1 = expf(l1 - mx), e2 = expf(l2 - mx);
    float s = 1.0f / (e0 + e1 + e2);
    out[g * 3 + 0] = e0 * s;
    out[g * 3 + 1] = e1 * s;
    out[g * 3 + 2] = e2 * s;
}

// ---------------- launch ----------------

extern "C" void kernel_launch(void* const* d_in, const int* in_sizes, int n_in,
                              void* d_out, int out_size, void* d_ws, size_t ws_size,
                              hipStream_t stream) {
    const float* x     = (const float*)d_in[0];
    const int*   ei    = (const int*)d_in[1];
    const float* ew    = (const float*)d_in[2];
    const int*   batch = (const int*)d_in[3];
    const float* W1    = (const float*)d_in[4];
    const float* b1    = (const float*)d_in[5];
    const float* W2    = (const float*)d_in[6];
    const float* b2    = (const float*)d_in[7];
    const float* W3    = (const float*)d_in[8];
    const float* b3    = (const float*)d_in[9];
    const float* lin_w = (const float*)d_in[10];
    const float* lin_b = (const float*)d_in[11];
    float* out = (float*)d_out;

    const int nN = in_sizes[0] / 4;       // 100000
    const int nE = in_sizes[2];           // 2500000
    const int G  = out_size / 3;          // 1000
    const int* row = ei;
    const int* col = ei + nE;

    const int NBUK = (nN + BN - 1) / BN;          // 782
    const int C    = (nE + CHUNK - 1) / CHUNK;    // 306

    // workspace layout (8B-aligned first)
    char* wsb = (char*)d_ws;
    ull*    sorted = (ull*)wsb;                                  // [nE]    20 MB
    uint*   csr4   = (uint*)(sorted + nE);                       // [nE]    10 MB
    float*  u_x    = (float*)(csr4 + nE);                        // [nN*4]  1.6 MB
    __half* t_a    = (__half*)(u_x + (size_t)nN * 4);            // [nN*32] 6.4 MB
    __half* t_b    = t_a + (size_t)nN * 32;                      // [nN*32] 6.4 MB
    __half* stage  = t_b + (size_t)nN * 32;                      // [nN*32] 6.4 MB
    int*    cntmat = (int*)(stage + (size_t)nN * 32);            // [C*NBUK] ~1 MB
    int*    tot    = cntmat + (size_t)C * NBUK;                  // [NBUK]
    int*    bb     = tot + NBUK;                                 // [NBUK+1]
    float*  dinv   = (float*)(bb + NBUK + 1);                    // [nN]
    int*    rowptr = (int*)(dinv + nN);                          // [nN+1]
    float*  sums   = (float*)(rowptr + nN + 1);                  // [G*32]
    float*  cnt    = sums + (size_t)G * 32;                      // [G]

    const int gW = (nN + (BLOCK / 64) - 1) / (BLOCK / 64);       // one wave per node

    // ---- build ----
    init_kernel<<<(G * 32 + BLOCK - 1) / BLOCK, BLOCK, 0, stream>>>(sums, cnt, rowptr, G, nN, nE);
    p1_kernel<<<C, BLOCK, 0, stream>>>(col, cntmat, nE, NBUK);
    p2a_kernel<<<(NBUK + 3) / 4, BLOCK, 0, stream>>>(cntmat, tot, C, NBUK);
    p2b_kernel<<<1, 1024, 0, stream>>>(tot, bb, NBUK, nE);
    p3_kernel<<<C, BLOCK, 0, stream>>>(row, col, ew, cntmat, bb, sorted, nE, NBUK);
    p4_kernel<<<NBUK, BLOCK, 0, stream>>>(sorted, bb, dinv, rowptr, csr4, nN);
    ux_kernel<<<(nN * 4 + BLOCK - 1) / BLOCK, BLOCK, 0, stream>>>(x, dinv, u_x, nN);

    // ---- layers ----
    layer1_pass<<<gW, BLOCK, 0, stream>>>(u_x, rowptr, csr4, dinv, W1, b1, W2, t_b, nN);
    layer_pass<false><<<gW, BLOCK, 0, stream>>>(t_b, rowptr, csr4, dinv, b2, W3, t_a, nullptr, nN);
    layer_pass<true><<<gW, BLOCK, 0, stream>>>(t_a, rowptr, csr4, dinv, b3, nullptr, nullptr, stage, nN);

    // ---- pooling + classifier ----
    pool_kernel<<<(nN + PB - 1) / PB, BLOCK, 0, stream>>>(stage, batch, sums, cnt, nN);
    final_kernel<<<(G + BLOCK - 1) / BLOCK, BLOCK, 0, stream>>>(sums, cnt, lin_w, lin_b, out, G);
}